// Round 1
// baseline (835.133 us; speedup 1.0000x reference)
//
#include <hip/hip_runtime.h>
#include <hip/hip_bf16.h>

#define ROWS   8192   // B*T
#define DIM    512
#define NCODES 8192
#define NCHUNK 16
#define BM     128
#define BN     128
#define BK     16
#define SUBT   ((NCODES / NCHUNK) / BN)   // 4 subtiles per chunk

// ---------------- Kernel 1: per-row mean / rstd ----------------
__global__ __launch_bounds__(256) void ln_stats_kernel(
    const float* __restrict__ x, float2* __restrict__ stats)
{
    const int wave = threadIdx.x >> 6;
    const int lane = threadIdx.x & 63;
    const int row  = blockIdx.x * 4 + wave;
    const float* xr = x + (size_t)row * DIM + lane * 8;
    float4 v0 = *(const float4*)(xr);
    float4 v1 = *(const float4*)(xr + 4);
    float s = (v0.x + v0.y) + (v0.z + v0.w) + (v1.x + v1.y) + (v1.z + v1.w);
    float q = v0.x*v0.x + v0.y*v0.y + v0.z*v0.z + v0.w*v0.w
            + v1.x*v1.x + v1.y*v1.y + v1.z*v1.z + v1.w*v1.w;
    #pragma unroll
    for (int off = 1; off < 64; off <<= 1) {
        s += __shfl_xor(s, off);
        q += __shfl_xor(q, off);
    }
    if (lane == 0) {
        float mu   = s * (1.0f / DIM);
        float var  = q * (1.0f / DIM) - mu * mu;
        float rstd = rsqrtf(var + 1e-5f);
        stats[row] = make_float2(mu, rstd);
    }
}

// ------- Kernel 2: fused LN-apply + GEMM (HxE^T) + running argmax -------
// grid (ROWS/BM, NCHUNK), 256 threads. Each block: 128 rows x 512-col chunk.
__global__ __launch_bounds__(256) void gemm_argmax_kernel(
    const float* __restrict__ x, const float* __restrict__ w,
    const float* __restrict__ b, const float* __restrict__ embd,
    const float2* __restrict__ stats,
    float* __restrict__ pval, int* __restrict__ pidx)
{
    __shared__ __align__(16) float Hs[BK][BM + 4];
    __shared__ __align__(16) float Es[BK][BN + 4];

    const int t   = threadIdx.x;
    const int tx  = t & 15;
    const int ty  = t >> 4;
    const int tx4 = tx * 4;
    const int ty4 = ty * 4;
    const int lr  = t >> 1;            // staging row 0..127
    const int kq  = (t & 1) * 8;       // k sub-offset 0 or 8

    const int r0 = blockIdx.x * BM;
    const int ch = blockIdx.y;

    const float2 st   = stats[r0 + lr];
    const float  arow = st.y;               // rstd
    const float  crow = -st.x * st.y;       // -mu*rstd  (h = x*arow+crow, then *w+b)

    float best[8];
    int   bidx[8];
    #pragma unroll
    for (int i = 0; i < 8; ++i) { best[i] = -3.4e38f; bidx[i] = 0; }

    const float* xr = x + (size_t)(r0 + lr) * DIM + kq;

    for (int s = 0; s < SUBT; ++s) {
        const int n0 = ch * (NCODES / NCHUNK) + s * BN;
        const float* er = embd + (size_t)(n0 + lr) * DIM + kq;

        float acc[8][8];
        #pragma unroll
        for (int i = 0; i < 8; ++i)
            #pragma unroll
            for (int j = 0; j < 8; ++j) acc[i][j] = 0.0f;

        for (int kk = 0; kk < DIM; kk += BK) {
            // ---- stage H (with LayerNorm applied) and E into LDS ----
            float4 xv0 = *(const float4*)(xr + kk);
            float4 xv1 = *(const float4*)(xr + kk + 4);
            float4 ev0 = *(const float4*)(er + kk);
            float4 ev1 = *(const float4*)(er + kk + 4);
            float4 wv0 = *(const float4*)(w + kk + kq);
            float4 wv1 = *(const float4*)(w + kk + kq + 4);
            float4 bv0 = *(const float4*)(b + kk + kq);
            float4 bv1 = *(const float4*)(b + kk + kq + 4);

            Hs[kq + 0][lr] = (xv0.x * arow + crow) * wv0.x + bv0.x;
            Hs[kq + 1][lr] = (xv0.y * arow + crow) * wv0.y + bv0.y;
            Hs[kq + 2][lr] = (xv0.z * arow + crow) * wv0.z + bv0.z;
            Hs[kq + 3][lr] = (xv0.w * arow + crow) * wv0.w + bv0.w;
            Hs[kq + 4][lr] = (xv1.x * arow + crow) * wv1.x + bv1.x;
            Hs[kq + 5][lr] = (xv1.y * arow + crow) * wv1.y + bv1.y;
            Hs[kq + 6][lr] = (xv1.z * arow + crow) * wv1.z + bv1.z;
            Hs[kq + 7][lr] = (xv1.w * arow + crow) * wv1.w + bv1.w;

            Es[kq + 0][lr] = ev0.x;
            Es[kq + 1][lr] = ev0.y;
            Es[kq + 2][lr] = ev0.z;
            Es[kq + 3][lr] = ev0.w;
            Es[kq + 4][lr] = ev1.x;
            Es[kq + 5][lr] = ev1.y;
            Es[kq + 6][lr] = ev1.z;
            Es[kq + 7][lr] = ev1.w;

            __syncthreads();

            #pragma unroll
            for (int k = 0; k < BK; ++k) {
                float4 a0 = *(const float4*)&Hs[k][ty4];
                float4 a1 = *(const float4*)&Hs[k][ty4 + 64];
                float4 b0 = *(const float4*)&Es[k][tx4];
                float4 b1 = *(const float4*)&Es[k][tx4 + 64];
                float av[8] = {a0.x, a0.y, a0.z, a0.w, a1.x, a1.y, a1.z, a1.w};
                float bv[8] = {b0.x, b0.y, b0.z, b0.w, b1.x, b1.y, b1.z, b1.w};
                #pragma unroll
                for (int i = 0; i < 8; ++i)
                    #pragma unroll
                    for (int j = 0; j < 8; ++j)
                        acc[i][j] += av[i] * bv[j];
            }

            __syncthreads();
        }

        // ---- fold this subtile into running per-row argmax ----
        #pragma unroll
        for (int j = 0; j < 8; ++j) {
            const int col = n0 + ((j < 4) ? (tx4 + j) : (64 + tx4 + (j - 4)));
            #pragma unroll
            for (int i = 0; i < 8; ++i) {
                if (acc[i][j] > best[i]) { best[i] = acc[i][j]; bidx[i] = col; }
            }
        }
    }

    // reduce across the 16 tx-lanes sharing each row group
    #pragma unroll
    for (int off = 1; off < 16; off <<= 1) {
        #pragma unroll
        for (int i = 0; i < 8; ++i) {
            float ov = __shfl_xor(best[i], off);
            int   oi = __shfl_xor(bidx[i], off);
            if (ov > best[i] || (ov == best[i] && oi < bidx[i])) {
                best[i] = ov; bidx[i] = oi;
            }
        }
    }

    if (tx == 0) {
        #pragma unroll
        for (int i = 0; i < 8; ++i) {
            const int lrow = (i < 4) ? (ty4 + i) : (64 + ty4 + (i - 4));
            const int row  = r0 + lrow;
            pval[(size_t)row * NCHUNK + ch] = best[i];
            pidx[(size_t)row * NCHUNK + ch] = bidx[i];
        }
    }
}

// ---------------- Kernel 3: final reduce + gather ----------------
__global__ __launch_bounds__(256) void finalize_kernel(
    const float* __restrict__ embd, const float* __restrict__ pval,
    const int* __restrict__ pidx, float* __restrict__ outq,
    float* __restrict__ outi)
{
    const int wv   = threadIdx.x >> 6;
    const int lane = threadIdx.x & 63;
    const int row  = blockIdx.x * 4 + wv;

    float bvv = -3.4e38f;
    int   bii = 0x7fffffff;
    if (lane < NCHUNK) {
        bvv = pval[(size_t)row * NCHUNK + lane];
        bii = pidx[(size_t)row * NCHUNK + lane];
    }
    #pragma unroll
    for (int off = 1; off < NCHUNK; off <<= 1) {
        float ov = __shfl_xor(bvv, off);
        int   oi = __shfl_xor(bii, off);
        if (ov > bvv || (ov == bvv && oi < bii)) { bvv = ov; bii = oi; }
    }
    const int idx = __shfl(bii, 0);

    const float* er = embd + (size_t)idx * DIM;
    float*       qr = outq + (size_t)row * DIM;
    *(float4*)(qr + lane * 4)       = *(const float4*)(er + lane * 4);
    *(float4*)(qr + 256 + lane * 4) = *(const float4*)(er + 256 + lane * 4);
    if (lane == 0) outi[row] = (float)idx;
}

extern "C" void kernel_launch(void* const* d_in, const int* in_sizes, int n_in,
                              void* d_out, int out_size, void* d_ws, size_t ws_size,
                              hipStream_t stream) {
    const float* x    = (const float*)d_in[0];
    const float* lnw  = (const float*)d_in[1];
    const float* lnb  = (const float*)d_in[2];
    const float* embd = (const float*)d_in[3];

    float* outq = (float*)d_out;                       // [8192*512] quantize
    float* outi = outq + (size_t)ROWS * DIM;           // [8192] idxs as float

    char*   ws    = (char*)d_ws;
    float2* stats = (float2*)ws;                                         // 64 KB
    float*  pval  = (float*)(ws + (size_t)ROWS * sizeof(float2));        // 512 KB
    int*    pidx  = (int*)(ws + (size_t)ROWS * sizeof(float2)
                              + (size_t)ROWS * NCHUNK * sizeof(float));  // 512 KB

    ln_stats_kernel<<<ROWS / 4, 256, 0, stream>>>(x, stats);

    dim3 g2(ROWS / BM, NCHUNK);
    gemm_argmax_kernel<<<g2, 256, 0, stream>>>(x, lnw, lnb, embd, stats, pval, pidx);

    finalize_kernel<<<ROWS / 4, 256, 0, stream>>>(embd, pval, pidx, outq, outi);
}

// Round 2
// 229.275 us; speedup vs baseline: 3.6425x; 3.6425x over previous
//
#include <hip/hip_runtime.h>
#include <hip/hip_bf16.h>

#define ROWS   8192
#define DIM    512
#define NCODES 8192
#define BM     128
#define BN     128
#define BK     32
#define NCHK   (NCODES / 64)          // 128 chunks of 64 cols (2 per block col-tile)
#define MARGIN 0.75f

using bf16x8 = __attribute__((ext_vector_type(8))) short;
using f32x4  = __attribute__((ext_vector_type(4))) float;

__device__ __forceinline__ void gload_lds16(const void* g, void* l) {
    __builtin_amdgcn_global_load_lds((const __attribute__((address_space(1))) void*)g,
                                     (__attribute__((address_space(3))) void*)l,
                                     16, 0, 0);
}

__device__ __forceinline__ unsigned short f2bf_rne(float f) {
    unsigned int u = __float_as_uint(f);
    u = (u + 0x7FFFu + ((u >> 16) & 1u)) >> 16;
    return (unsigned short)u;
}

// merge top2 (u1,j1,u2,j2) into (v1,i1,v2,i2); lower index wins ties
__device__ __forceinline__ void merge2(float& v1, int& i1, float& v2, int& i2,
                                       float u1, int j1, float u2, int j2) {
    if (u1 > v1 || (u1 == v1 && j1 < i1)) {
        float t1 = v1; int t2 = i1;
        v1 = u1; i1 = j1;
        if (t1 > u2 || (t1 == u2 && t2 < j2)) { v2 = t1; i2 = t2; }
        else                                  { v2 = u2; i2 = j2; }
    } else {
        if (u1 > v2 || (u1 == v2 && j1 < i2)) { v2 = u1; i2 = j1; }
    }
}

// ---------- Kernel 1: LN stats + bf16(h) rows, and bf16(embd) rows ----------
__global__ __launch_bounds__(256) void prep_kernel(
    const float* __restrict__ x, const float* __restrict__ lw,
    const float* __restrict__ lb, const float* __restrict__ embd,
    float2* __restrict__ stats, unsigned short* __restrict__ Hb,
    unsigned short* __restrict__ Eb)
{
    const int w    = threadIdx.x >> 6;
    const int lane = threadIdx.x & 63;
    const int b    = blockIdx.x;

    if (b < 2048) {                       // LayerNorm rows -> Hb + stats
        const int row = b * 4 + w;
        const float* xr = x + (size_t)row * DIM + lane * 8;
        float4 v0 = *(const float4*)(xr);
        float4 v1 = *(const float4*)(xr + 4);
        float s = (v0.x + v0.y) + (v0.z + v0.w) + (v1.x + v1.y) + (v1.z + v1.w);
        float q = v0.x*v0.x + v0.y*v0.y + v0.z*v0.z + v0.w*v0.w
                + v1.x*v1.x + v1.y*v1.y + v1.z*v1.z + v1.w*v1.w;
        #pragma unroll
        for (int off = 1; off < 64; off <<= 1) {
            s += __shfl_xor(s, off);
            q += __shfl_xor(q, off);
        }
        float mu   = s * (1.0f / DIM);
        float var  = q * (1.0f / DIM) - mu * mu;
        float rstd = rsqrtf(var + 1e-5f);
        if (lane == 0) stats[row] = make_float2(mu, rstd);

        float4 w0 = *(const float4*)(lw + lane * 8);
        float4 w1 = *(const float4*)(lw + lane * 8 + 4);
        float4 b0 = *(const float4*)(lb + lane * 8);
        float4 b1 = *(const float4*)(lb + lane * 8 + 4);
        float hv[8] = {
            (v0.x - mu) * rstd * w0.x + b0.x, (v0.y - mu) * rstd * w0.y + b0.y,
            (v0.z - mu) * rstd * w0.z + b0.z, (v0.w - mu) * rstd * w0.w + b0.w,
            (v1.x - mu) * rstd * w1.x + b1.x, (v1.y - mu) * rstd * w1.y + b1.y,
            (v1.z - mu) * rstd * w1.z + b1.z, (v1.w - mu) * rstd * w1.w + b1.w };
        union { unsigned short u[8]; uint4 v; } p;
        #pragma unroll
        for (int j = 0; j < 8; ++j) p.u[j] = f2bf_rne(hv[j]);
        *(uint4*)(Hb + (size_t)row * DIM + lane * 8) = p.v;
    } else {                              // embd rows -> Eb
        const int row = (b - 2048) * 4 + w;
        const float* er = embd + (size_t)row * DIM + lane * 8;
        float4 v0 = *(const float4*)(er);
        float4 v1 = *(const float4*)(er + 4);
        float ev[8] = { v0.x, v0.y, v0.z, v0.w, v1.x, v1.y, v1.z, v1.w };
        union { unsigned short u[8]; uint4 v; } p;
        #pragma unroll
        for (int j = 0; j < 8; ++j) p.u[j] = f2bf_rne(ev[j]);
        *(uint4*)(Eb + (size_t)row * DIM + lane * 8) = p.v;
    }
}

// ---------- Kernel 2: bf16 MFMA GEMM + per-(row, 64-col-chunk) top-2 ----------
// grid (NCODES/BN, ROWS/BM), 256 threads (4 waves, 2x2), m97-style 2-barrier loop
__global__ __launch_bounds__(256) void gemm_argmax_kernel(
    const unsigned short* __restrict__ Hb, const unsigned short* __restrict__ Eb,
    float* __restrict__ pval, int* __restrict__ pidx)
{
    __shared__ __align__(16) unsigned short As[BM * BK];
    __shared__ __align__(16) unsigned short Bs[BN * BK];

    const int t    = threadIdx.x;
    const int w    = t >> 6;
    const int lane = t & 63;
    const int r    = lane & 15;        // col-within-16 / A-row-within-16
    const int q    = lane >> 4;        // k-group / C-row-quad
    const int wr   = w >> 1;
    const int wc   = w & 1;

    const int r0 = blockIdx.y * BM;
    const int n0 = blockIdx.x * BN;

    f32x4 acc[4][4];
    #pragma unroll
    for (int m = 0; m < 4; ++m)
        #pragma unroll
        for (int n = 0; n < 4; ++n) acc[m][n] = (f32x4){0.f, 0.f, 0.f, 0.f};

    for (int kt = 0; kt < DIM / BK; ++kt) {
        const int kk = kt * BK;
        #pragma unroll
        for (int i = 0; i < 2; ++i) {
            const int seg  = i * 4 + w;            // 8 segs of 1 KiB per tile
            const int e    = seg * 64 + lane;      // 16B-unit index in tile
            const int arow = e >> 2;               // 4 x 16B per 64B row
            const int acol = (e & 3) * 8;          // bf16 col offset
            gload_lds16(Hb + (size_t)(r0 + arow) * DIM + kk + acol, &As[seg * 512]);
            gload_lds16(Eb + (size_t)(n0 + arow) * DIM + kk + acol, &Bs[seg * 512]);
        }
        __syncthreads();

        bf16x8 a[4], b[4];
        #pragma unroll
        for (int m = 0; m < 4; ++m)
            a[m] = *(const bf16x8*)&As[(wr * 64 + m * 16 + r) * BK + q * 8];
        #pragma unroll
        for (int n = 0; n < 4; ++n)
            b[n] = *(const bf16x8*)&Bs[(wc * 64 + n * 16 + r) * BK + q * 8];
        #pragma unroll
        for (int m = 0; m < 4; ++m)
            #pragma unroll
            for (int n = 0; n < 4; ++n)
                acc[m][n] = __builtin_amdgcn_mfma_f32_16x16x32_bf16(a[m], b[n], acc[m][n], 0, 0, 0);
        __syncthreads();
    }

    // ---- epilogue: per-row top-2 over this wave's 64 cols ----
    const int ch    = blockIdx.x * 2 + wc;          // 64-col chunk id
    const int cbase = n0 + wc * 64;
    #pragma unroll
    for (int m = 0; m < 4; ++m) {
        #pragma unroll
        for (int reg = 0; reg < 4; ++reg) {
            float v1 = acc[m][0][reg]; int i1 = cbase + r;
            float v2 = -3.4e38f;       int i2 = 0x7fffffff;
            #pragma unroll
            for (int n = 1; n < 4; ++n) {
                float vv = acc[m][n][reg];
                int   cc = cbase + n * 16 + r;
                if (vv > v1)      { v2 = v1; i2 = i1; v1 = vv; i1 = cc; }
                else if (vv > v2) { v2 = vv; i2 = cc; }
            }
            #pragma unroll
            for (int off = 1; off < 16; off <<= 1) {
                float u1 = __shfl_xor(v1, off);
                int   j1 = __shfl_xor(i1, off);
                float u2 = __shfl_xor(v2, off);
                int   j2 = __shfl_xor(i2, off);
                merge2(v1, i1, v2, i2, u1, j1, u2, j2);
            }
            if (r == 0) {
                const int row = r0 + wr * 64 + m * 16 + q * 4 + reg;
                const size_t base = (size_t)row * (NCHK * 2) + ch * 2;
                pval[base] = v1; pval[base + 1] = v2;
                pidx[base] = i1; pidx[base + 1] = i2;
            }
        }
    }
}

// ---------- Kernel 3: exact fp32 re-check of candidates + gather ----------
__global__ __launch_bounds__(256) void finalize_kernel(
    const float* __restrict__ x, const float* __restrict__ lw,
    const float* __restrict__ lb, const float* __restrict__ embd,
    const float2* __restrict__ stats,
    const float* __restrict__ pval, const int* __restrict__ pidx,
    float* __restrict__ outq, float* __restrict__ outi)
{
    const int w    = threadIdx.x >> 6;
    const int lane = threadIdx.x & 63;
    const int row  = blockIdx.x * 4 + w;

    // candidates: 256 approx (val, idx) per row
    const float4 cv = *(const float4*)&pval[(size_t)row * 256 + lane * 4];
    const int4   ci = *(const int4*)  &pidx[(size_t)row * 256 + lane * 4];
    float vv[4] = { cv.x, cv.y, cv.z, cv.w };
    int   ii[4] = { ci.x, ci.y, ci.z, ci.w };

    float M = fmaxf(fmaxf(vv[0], vv[1]), fmaxf(vv[2], vv[3]));
    #pragma unroll
    for (int off = 1; off < 64; off <<= 1) M = fmaxf(M, __shfl_xor(M, off));
    const float T = M - MARGIN;

    // exact h for this row
    const float2 st = stats[row];
    const float mu = st.x, rstd = st.y;
    const float* xr = x + (size_t)row * DIM + lane * 8;
    float4 x0 = *(const float4*)(xr);
    float4 x1 = *(const float4*)(xr + 4);
    float4 w0 = *(const float4*)(lw + lane * 8);
    float4 w1 = *(const float4*)(lw + lane * 8 + 4);
    float4 b0 = *(const float4*)(lb + lane * 8);
    float4 b1 = *(const float4*)(lb + lane * 8 + 4);
    float h[8] = {
        (x0.x - mu) * rstd * w0.x + b0.x, (x0.y - mu) * rstd * w0.y + b0.y,
        (x0.z - mu) * rstd * w0.z + b0.z, (x0.w - mu) * rstd * w0.w + b0.w,
        (x1.x - mu) * rstd * w1.x + b1.x, (x1.y - mu) * rstd * w1.y + b1.y,
        (x1.z - mu) * rstd * w1.z + b1.z, (x1.w - mu) * rstd * w1.w + b1.w };

    float bestv = -3.4e38f; int besti = 0x7fffffff;
    #pragma unroll
    for (int s = 0; s < 4; ++s) {
        unsigned long long msk = __ballot(vv[s] >= T);
        while (msk) {
            const int L = __ffsll(msk) - 1;
            msk &= msk - 1;
            const int cand = __shfl(ii[s], L);
            const float* er = embd + (size_t)cand * DIM + lane * 8;
            float4 e0 = *(const float4*)er;
            float4 e1 = *(const float4*)(er + 4);
            float d = h[0]*e0.x + h[1]*e0.y + h[2]*e0.z + h[3]*e0.w
                    + h[4]*e1.x + h[5]*e1.y + h[6]*e1.z + h[7]*e1.w;
            #pragma unroll
            for (int off = 1; off < 64; off <<= 1) d += __shfl_xor(d, off);
            if (d > bestv || (d == bestv && cand < besti)) { bestv = d; besti = cand; }
        }
    }

    const float* er = embd + (size_t)besti * DIM + lane * 8;
    float4 q0 = *(const float4*)er;
    float4 q1 = *(const float4*)(er + 4);
    float* qr = outq + (size_t)row * DIM + lane * 8;
    *(float4*)(qr)     = q0;
    *(float4*)(qr + 4) = q1;
    if (lane == 0) outi[row] = (float)besti;
}

extern "C" void kernel_launch(void* const* d_in, const int* in_sizes, int n_in,
                              void* d_out, int out_size, void* d_ws, size_t ws_size,
                              hipStream_t stream) {
    const float* x    = (const float*)d_in[0];
    const float* lnw  = (const float*)d_in[1];
    const float* lnb  = (const float*)d_in[2];
    const float* embd = (const float*)d_in[3];

    float* outq = (float*)d_out;
    float* outi = outq + (size_t)ROWS * DIM;

    char* ws = (char*)d_ws;
    float2*         stats = (float2*)ws;                       // 64 KiB
    unsigned short* Hb    = (unsigned short*)(ws + (1 << 16));                 // 8 MiB
    unsigned short* Eb    = (unsigned short*)(ws + (1 << 16) + (8 << 20));     // 8 MiB
    float*          pval  = (float*)(ws + (1 << 16) + (16 << 20));             // 8 MiB
    int*            pidx  = (int*)  (ws + (1 << 16) + (24 << 20));             // 8 MiB

    prep_kernel<<<4096, 256, 0, stream>>>(x, lnw, lnb, embd, stats, Hb, Eb);

    dim3 g2(NCODES / BN, ROWS / BM);
    gemm_argmax_kernel<<<g2, 256, 0, stream>>>(Hb, Eb, pval, pidx);

    finalize_kernel<<<ROWS / 4, 256, 0, stream>>>(x, lnw, lnb, embd, stats,
                                                  pval, pidx, outq, outi);
}

// Round 3
// 168.441 us; speedup vs baseline: 4.9580x; 1.3612x over previous
//
#include <hip/hip_runtime.h>
#include <hip/hip_bf16.h>

#define ROWS   8192
#define DIM    512
#define NCODES 8192
#define BM     256
#define BN     256
#define BK     32
#define NT     (DIM / BK)             // 16 K-tiles
#define MARGIN 0.75f

using bf16x8 = __attribute__((ext_vector_type(8))) short;
using f32x4  = __attribute__((ext_vector_type(4))) float;
typedef unsigned short ushort_t;

__device__ __forceinline__ void gload_lds16(const void* g, void* l) {
    __builtin_amdgcn_global_load_lds((const __attribute__((address_space(1))) void*)g,
                                     (__attribute__((address_space(3))) void*)l,
                                     16, 0, 0);
}

__device__ __forceinline__ unsigned short f2bf_rne(float f) {
    unsigned int u = __float_as_uint(f);
    u = (u + 0x7FFFu + ((u >> 16) & 1u)) >> 16;
    return (unsigned short)u;
}

// ---------- Kernel 1: LN stats + bf16(h) rows, and bf16(embd) rows ----------
__global__ __launch_bounds__(256) void prep_kernel(
    const float* __restrict__ x, const float* __restrict__ lw,
    const float* __restrict__ lb, const float* __restrict__ embd,
    float2* __restrict__ stats, ushort_t* __restrict__ Hb,
    ushort_t* __restrict__ Eb)
{
    const int w    = threadIdx.x >> 6;
    const int lane = threadIdx.x & 63;
    const int b    = blockIdx.x;

    if (b < 2048) {
        const int row = b * 4 + w;
        const float* xr = x + (size_t)row * DIM + lane * 8;
        float4 v0 = *(const float4*)(xr);
        float4 v1 = *(const float4*)(xr + 4);
        float s = (v0.x + v0.y) + (v0.z + v0.w) + (v1.x + v1.y) + (v1.z + v1.w);
        float q = v0.x*v0.x + v0.y*v0.y + v0.z*v0.z + v0.w*v0.w
                + v1.x*v1.x + v1.y*v1.y + v1.z*v1.z + v1.w*v1.w;
        #pragma unroll
        for (int off = 1; off < 64; off <<= 1) {
            s += __shfl_xor(s, off);
            q += __shfl_xor(q, off);
        }
        float mu   = s * (1.0f / DIM);
        float var  = q * (1.0f / DIM) - mu * mu;
        float rstd = rsqrtf(var + 1e-5f);
        if (lane == 0) stats[row] = make_float2(mu, rstd);

        float4 w0 = *(const float4*)(lw + lane * 8);
        float4 w1 = *(const float4*)(lw + lane * 8 + 4);
        float4 b0 = *(const float4*)(lb + lane * 8);
        float4 b1 = *(const float4*)(lb + lane * 8 + 4);
        float hv[8] = {
            (v0.x - mu) * rstd * w0.x + b0.x, (v0.y - mu) * rstd * w0.y + b0.y,
            (v0.z - mu) * rstd * w0.z + b0.z, (v0.w - mu) * rstd * w0.w + b0.w,
            (v1.x - mu) * rstd * w1.x + b1.x, (v1.y - mu) * rstd * w1.y + b1.y,
            (v1.z - mu) * rstd * w1.z + b1.z, (v1.w - mu) * rstd * w1.w + b1.w };
        union { unsigned short u[8]; uint4 v; } p;
        #pragma unroll
        for (int j = 0; j < 8; ++j) p.u[j] = f2bf_rne(hv[j]);
        *(uint4*)(Hb + (size_t)row * DIM + lane * 8) = p.v;
    } else {
        const int row = (b - 2048) * 4 + w;
        const float* er = embd + (size_t)row * DIM + lane * 8;
        float4 v0 = *(const float4*)(er);
        float4 v1 = *(const float4*)(er + 4);
        float ev[8] = { v0.x, v0.y, v0.z, v0.w, v1.x, v1.y, v1.z, v1.w };
        union { unsigned short u[8]; uint4 v; } p;
        #pragma unroll
        for (int j = 0; j < 8; ++j) p.u[j] = f2bf_rne(ev[j]);
        *(uint4*)(Eb + (size_t)row * DIM + lane * 8) = p.v;
    }
}

// ---------- Kernel 2: 256x256 bf16 MFMA GEMM, triple-buffer counted-vmcnt ----------
// 512 threads = 8 waves (2 row-halves x 4 col-quarters). Per-wave output 128x64.
// LDS: 3 bufs x (A 16KB + B 16KB) = 96KB. T2 swizzle: byte ^= ((row>>1)&3)<<4.
__global__ __launch_bounds__(512, 2) void gemm_argmax_kernel(
    const ushort_t* __restrict__ Hb, const ushort_t* __restrict__ Eb,
    float* __restrict__ pval, int* __restrict__ pidx)
{
    __shared__ __align__(16) ushort_t As[3][BM * BK];
    __shared__ __align__(16) ushort_t Bs[3][BN * BK];

    const int t    = threadIdx.x;
    const int w    = t >> 6;
    const int lane = t & 63;
    const int r_   = lane & 15;
    const int g    = lane >> 4;
    const int wr   = w >> 2;          // row half (0,1)
    const int wc   = w & 3;           // col quarter (0..3)

    // T1: XCD-region remap. HW: XCD = bid % 8. XCD x owns tile-rows 4x..4x+3,
    // all 32 col-tiles, col-major order -> per-XCD L2 working set ~3MB.
    const int bid  = blockIdx.x;
    const int slot = bid >> 3;
    const int trow = ((bid & 7) << 2) | (slot & 3);
    const int tcol = slot >> 2;
    const int r0 = trow * BM;
    const int n0 = tcol * BN;

    // ---- staging geometry: 32 x 1KB gload_lds per tile, wave w does insts {2w, 2w+1}
    // dest tile byte d = j*1024 + lane*16 -> drow = j*16 + (lane>>2), dcol = (lane&3)*16.
    // inverse-swizzled SOURCE: logical col byte = dcol ^ ((drow>>1)&3)<<4.
    const int arow0 = w * 32 + (lane >> 2);
    const int arow1 = arow0 + 16;
    const int lcb0  = ((lane & 3) * 16) ^ (((arow0 >> 1) & 3) << 4);
    const int lcb1  = ((lane & 3) * 16) ^ (((arow1 >> 1) & 3) << 4);
    const ushort_t* srcA0 = Hb + (size_t)(r0 + arow0) * DIM + (lcb0 >> 1);
    const ushort_t* srcA1 = Hb + (size_t)(r0 + arow1) * DIM + (lcb1 >> 1);
    const ushort_t* srcB0 = Eb + (size_t)(n0 + arow0) * DIM + (lcb0 >> 1);
    const ushort_t* srcB1 = Eb + (size_t)(n0 + arow1) * DIM + (lcb1 >> 1);
    const int j0u = (w * 2) * 512;        // ushort offset of inst dest
    const int j1u = (w * 2 + 1) * 512;

    // ---- swizzled ds_read bases (byte offsets within a buffer) ----
    const int swz   = ((r_ >> 1) & 3) << 4;
    const int abase = (wr * 128 + r_) * 64 + ((g * 16) ^ swz);   // + m*1024
    const int bbase = (wc * 64  + r_) * 64 + ((g * 16) ^ swz);   // + n*1024

    f32x4 acc[8][4];
    #pragma unroll
    for (int m = 0; m < 8; ++m)
        #pragma unroll
        for (int n = 0; n < 4; ++n) acc[m][n] = (f32x4){0.f, 0.f, 0.f, 0.f};

#define STAGE(T, BUF) do {                                          \
        const int _ko = (T) * BK;                                   \
        gload_lds16(srcA0 + _ko, &As[BUF][j0u]);                    \
        gload_lds16(srcA1 + _ko, &As[BUF][j1u]);                    \
        gload_lds16(srcB0 + _ko, &Bs[BUF][j0u]);                    \
        gload_lds16(srcB1 + _ko, &Bs[BUF][j1u]);                    \
    } while (0)

#define COMPUTE(BUF) do {                                           \
        bf16x8 a[8], b[4];                                          \
        _Pragma("unroll")                                           \
        for (int m = 0; m < 8; ++m)                                 \
            a[m] = *(const bf16x8*)((const char*)&As[BUF][0] + abase + m * 1024); \
        _Pragma("unroll")                                           \
        for (int n = 0; n < 4; ++n)                                 \
            b[n] = *(const bf16x8*)((const char*)&Bs[BUF][0] + bbase + n * 1024); \
        __builtin_amdgcn_s_setprio(1);                              \
        _Pragma("unroll")                                           \
        for (int m = 0; m < 8; ++m)                                 \
            _Pragma("unroll")                                       \
            for (int n = 0; n < 4; ++n)                             \
                acc[m][n] = __builtin_amdgcn_mfma_f32_16x16x32_bf16(a[m], b[n], acc[m][n], 0, 0, 0); \
        __builtin_amdgcn_s_setprio(0);                              \
    } while (0)

#define K_ITER(T, BUF, SBUF, VMSTR) do {                            \
        if ((T) + 2 < NT) STAGE((T) + 2, SBUF);                     \
        asm volatile("s_waitcnt vmcnt(" VMSTR ")" ::: "memory");    \
        __builtin_amdgcn_s_barrier();                               \
        COMPUTE(BUF);                                               \
        asm volatile("" ::: "memory");                              \
        __builtin_amdgcn_s_barrier();                               \
    } while (0)

    // prologue: 2 tiles in flight
    STAGE(0, 0);
    STAGE(1, 1);
    // invariant at loop head: outstanding = loads(t) + loads(t+1) = 8
    K_ITER(0,  0, 2, "8");
    K_ITER(1,  1, 0, "8");
    K_ITER(2,  2, 1, "8");
    K_ITER(3,  0, 2, "8");
    K_ITER(4,  1, 0, "8");
    K_ITER(5,  2, 1, "8");
    K_ITER(6,  0, 2, "8");
    K_ITER(7,  1, 0, "8");
    K_ITER(8,  2, 1, "8");
    K_ITER(9,  0, 2, "8");
    K_ITER(10, 1, 0, "8");
    K_ITER(11, 2, 1, "8");
    K_ITER(12, 0, 2, "8");
    K_ITER(13, 1, 0, "8");
    K_ITER(14, 2, 1, "4");   // no stage issued; wait loads(14)
    K_ITER(15, 0, 1, "0");   // no stage issued; wait loads(15)

#undef K_ITER
#undef COMPUTE
#undef STAGE

    // ---- epilogue: per-row top-2 over this wave's 64-col chunk ----
    const int cb = n0 + wc * 64;
    #pragma unroll
    for (int m = 0; m < 8; ++m) {
        #pragma unroll
        for (int reg = 0; reg < 4; ++reg) {
            float v1 = acc[m][0][reg]; int i1 = cb + r_;
            float v2 = -3.4e38f;       int i2 = 0;
            #pragma unroll
            for (int n = 1; n < 4; ++n) {
                float vv = acc[m][n][reg];
                int   cc = cb + n * 16 + r_;
                if (vv > v1)      { v2 = v1; i2 = i1; v1 = vv; i1 = cc; }
                else if (vv > v2) { v2 = vv; i2 = cc; }
            }
            #pragma unroll
            for (int off = 1; off < 16; off <<= 1) {
                float u1 = __shfl_xor(v1, off);
                int   j1 = __shfl_xor(i1, off);
                float u2 = __shfl_xor(v2, off);
                int   j2 = __shfl_xor(i2, off);
                if (u1 > v1) {
                    if (v1 > u2) { v2 = v1; i2 = i1; }
                    else         { v2 = u2; i2 = j2; }
                    v1 = u1; i1 = j1;
                } else if (u1 > v2) { v2 = u1; i2 = j1; }
            }
            if (r_ == 0) {
                const int row  = r0 + wr * 128 + m * 16 + g * 4 + reg;
                const size_t base = (size_t)row * 256 + (n0 >> 5) + wc * 2;
                pval[base] = v1; pval[base + 1] = v2;
                pidx[base] = i1; pidx[base + 1] = i2;
            }
        }
    }
}

// ---------- Kernel 3: exact fp32 re-check of candidates + gather ----------
__global__ __launch_bounds__(256) void finalize_kernel(
    const float* __restrict__ x, const float* __restrict__ lw,
    const float* __restrict__ lb, const float* __restrict__ embd,
    const float2* __restrict__ stats,
    const float* __restrict__ pval, const int* __restrict__ pidx,
    float* __restrict__ outq, float* __restrict__ outi)
{
    const int w    = threadIdx.x >> 6;
    const int lane = threadIdx.x & 63;
    const int row  = blockIdx.x * 4 + w;

    const float4 cv = *(const float4*)&pval[(size_t)row * 256 + lane * 4];
    const int4   ci = *(const int4*)  &pidx[(size_t)row * 256 + lane * 4];
    float vv[4] = { cv.x, cv.y, cv.z, cv.w };
    int   ii[4] = { ci.x, ci.y, ci.z, ci.w };

    float M = fmaxf(fmaxf(vv[0], vv[1]), fmaxf(vv[2], vv[3]));
    #pragma unroll
    for (int off = 1; off < 64; off <<= 1) M = fmaxf(M, __shfl_xor(M, off));
    const float T = M - MARGIN;

    const float2 st = stats[row];
    const float mu = st.x, rstd = st.y;
    const float* xr = x + (size_t)row * DIM + lane * 8;
    float4 x0 = *(const float4*)(xr);
    float4 x1 = *(const float4*)(xr + 4);
    float4 w0 = *(const float4*)(lw + lane * 8);
    float4 w1 = *(const float4*)(lw + lane * 8 + 4);
    float4 b0 = *(const float4*)(lb + lane * 8);
    float4 b1 = *(const float4*)(lb + lane * 8 + 4);
    float h[8] = {
        (x0.x - mu) * rstd * w0.x + b0.x, (x0.y - mu) * rstd * w0.y + b0.y,
        (x0.z - mu) * rstd * w0.z + b0.z, (x0.w - mu) * rstd * w0.w + b0.w,
        (x1.x - mu) * rstd * w1.x + b1.x, (x1.y - mu) * rstd * w1.y + b1.y,
        (x1.z - mu) * rstd * w1.z + b1.z, (x1.w - mu) * rstd * w1.w + b1.w };

    float bestv = -3.4e38f; int besti = 0x7fffffff;
    #pragma unroll
    for (int s = 0; s < 4; ++s) {
        unsigned long long msk = __ballot(vv[s] >= T);
        while (msk) {
            const int L = __ffsll(msk) - 1;
            msk &= msk - 1;
            const int cand = __shfl(ii[s], L);
            const float* er = embd + (size_t)cand * DIM + lane * 8;
            float4 e0 = *(const float4*)er;
            float4 e1 = *(const float4*)(er + 4);
            float d = h[0]*e0.x + h[1]*e0.y + h[2]*e0.z + h[3]*e0.w
                    + h[4]*e1.x + h[5]*e1.y + h[6]*e1.z + h[7]*e1.w;
            #pragma unroll
            for (int off = 1; off < 64; off <<= 1) d += __shfl_xor(d, off);
            if (d > bestv || (d == bestv && cand < besti)) { bestv = d; besti = cand; }
        }
    }

    const float* er = embd + (size_t)besti * DIM + lane * 8;
    float4 q0 = *(const float4*)er;
    float4 q1 = *(const float4*)(er + 4);
    float* qr = outq + (size_t)row * DIM + lane * 8;
    *(float4*)(qr)     = q0;
    *(float4*)(qr + 4) = q1;
    if (lane == 0) outi[row] = (float)besti;
}

extern "C" void kernel_launch(void* const* d_in, const int* in_sizes, int n_in,
                              void* d_out, int out_size, void* d_ws, size_t ws_size,
                              hipStream_t stream) {
    const float* x    = (const float*)d_in[0];
    const float* lnw  = (const float*)d_in[1];
    const float* lnb  = (const float*)d_in[2];
    const float* embd = (const float*)d_in[3];

    float* outq = (float*)d_out;
    float* outi = outq + (size_t)ROWS * DIM;

    char* ws = (char*)d_ws;
    float2*   stats = (float2*)ws;                                   // 64 KiB
    ushort_t* Hb    = (ushort_t*)(ws + (1 << 16));                   // 8 MiB
    ushort_t* Eb    = (ushort_t*)(ws + (1 << 16) + (8 << 20));       // 8 MiB
    float*    pval  = (float*)(ws + (1 << 16) + (16 << 20));         // 8 MiB
    int*      pidx  = (int*)  (ws + (1 << 16) + (24 << 20));         // 8 MiB

    prep_kernel<<<4096, 256, 0, stream>>>(x, lnw, lnb, embd, stats, Hb, Eb);

    gemm_argmax_kernel<<<1024, 512, 0, stream>>>(Hb, Eb, pval, pidx);

    finalize_kernel<<<ROWS / 4, 256, 0, stream>>>(x, lnw, lnb, embd, stats,
                                                  pval, pidx, outq, outi);
}

// Round 4
// 157.418 us; speedup vs baseline: 5.3052x; 1.0700x over previous
//
#include <hip/hip_runtime.h>
#include <hip/hip_bf16.h>

#define ROWS   8192
#define DIM    512
#define NCODES 8192
#define BM     256
#define BN     256
#define BK     32
#define NT     (DIM / BK)             // 16 K-tiles
#define MARGIN 0.75f

using bf16x8 = __attribute__((ext_vector_type(8))) short;
using f32x4  = __attribute__((ext_vector_type(4))) float;
typedef unsigned short ushort_t;

__device__ __forceinline__ void gload_lds16(const void* g, void* l) {
    __builtin_amdgcn_global_load_lds((const __attribute__((address_space(1))) void*)g,
                                     (__attribute__((address_space(3))) void*)l,
                                     16, 0, 0);
}

__device__ __forceinline__ unsigned short f2bf_rne(float f) {
    unsigned int u = __float_as_uint(f);
    u = (u + 0x7FFFu + ((u >> 16) & 1u)) >> 16;
    return (unsigned short)u;
}

// ---------- Kernel 1: LN stats + bf16(h) rows, and bf16(embd) rows ----------
__global__ __launch_bounds__(256) void prep_kernel(
    const float* __restrict__ x, const float* __restrict__ lw,
    const float* __restrict__ lb, const float* __restrict__ embd,
    float2* __restrict__ stats, ushort_t* __restrict__ Hb,
    ushort_t* __restrict__ Eb)
{
    const int w    = threadIdx.x >> 6;
    const int lane = threadIdx.x & 63;
    const int b    = blockIdx.x;

    if (b < 2048) {
        const int row = b * 4 + w;
        const float* xr = x + (size_t)row * DIM + lane * 8;
        float4 v0 = *(const float4*)(xr);
        float4 v1 = *(const float4*)(xr + 4);
        float s = (v0.x + v0.y) + (v0.z + v0.w) + (v1.x + v1.y) + (v1.z + v1.w);
        float q = v0.x*v0.x + v0.y*v0.y + v0.z*v0.z + v0.w*v0.w
                + v1.x*v1.x + v1.y*v1.y + v1.z*v1.z + v1.w*v1.w;
        #pragma unroll
        for (int off = 1; off < 64; off <<= 1) {
            s += __shfl_xor(s, off);
            q += __shfl_xor(q, off);
        }
        float mu   = s * (1.0f / DIM);
        float var  = q * (1.0f / DIM) - mu * mu;
        float rstd = rsqrtf(var + 1e-5f);
        if (lane == 0) stats[row] = make_float2(mu, rstd);

        float4 w0 = *(const float4*)(lw + lane * 8);
        float4 w1 = *(const float4*)(lw + lane * 8 + 4);
        float4 b0 = *(const float4*)(lb + lane * 8);
        float4 b1 = *(const float4*)(lb + lane * 8 + 4);
        float hv[8] = {
            (v0.x - mu) * rstd * w0.x + b0.x, (v0.y - mu) * rstd * w0.y + b0.y,
            (v0.z - mu) * rstd * w0.z + b0.z, (v0.w - mu) * rstd * w0.w + b0.w,
            (v1.x - mu) * rstd * w1.x + b1.x, (v1.y - mu) * rstd * w1.y + b1.y,
            (v1.z - mu) * rstd * w1.z + b1.z, (v1.w - mu) * rstd * w1.w + b1.w };
        union { unsigned short u[8]; uint4 v; } p;
        #pragma unroll
        for (int j = 0; j < 8; ++j) p.u[j] = f2bf_rne(hv[j]);
        *(uint4*)(Hb + (size_t)row * DIM + lane * 8) = p.v;
    } else {
        const int row = (b - 2048) * 4 + w;
        const float* er = embd + (size_t)row * DIM + lane * 8;
        float4 v0 = *(const float4*)(er);
        float4 v1 = *(const float4*)(er + 4);
        float ev[8] = { v0.x, v0.y, v0.z, v0.w, v1.x, v1.y, v1.z, v1.w };
        union { unsigned short u[8]; uint4 v; } p;
        #pragma unroll
        for (int j = 0; j < 8; ++j) p.u[j] = f2bf_rne(ev[j]);
        *(uint4*)(Eb + (size_t)row * DIM + lane * 8) = p.v;
    }
}

// ---------- Kernel 2: 256x256 bf16 MFMA GEMM, 4-slot ring, phase pipeline ----
// 512 threads = 8 waves (2 row-halves x 4 col-quarters). Per-wave output 128x64.
// LDS: 4 ring slots x (A 16KB + B 16KB) = 128KB. T2 swizzle byte^=((row>>1)&3)<<4.
// Per K-tile: stageA(kt+2); vmcnt(6); barrier; 12 ds_read; prio1 16 MFMA;
//             stageB(kt+2); 16 MFMA prio0.   (counted vmcnt: 6,...,6,4,0)
__global__ __launch_bounds__(512, 2) void gemm_argmax_kernel(
    const ushort_t* __restrict__ Hb, const ushort_t* __restrict__ Eb,
    float* __restrict__ pval, int* __restrict__ pidx)
{
    __shared__ __align__(16) ushort_t As[4][BM * BK];
    __shared__ __align__(16) ushort_t Bs[4][BN * BK];

    const int t    = threadIdx.x;
    const int w    = t >> 6;
    const int lane = t & 63;
    const int r_   = lane & 15;
    const int g    = lane >> 4;
    const int wr   = w >> 2;          // row half (0,1)
    const int wc   = w & 3;           // col quarter (0..3)

    // T1: XCD-region remap (XCD = bid % 8 owns 4 tile-rows, col-major order)
    const int bid  = blockIdx.x;
    const int slot = bid >> 3;
    const int trow = ((bid & 7) << 2) | (slot & 3);
    const int tcol = slot >> 2;
    const int r0 = trow * BM;
    const int n0 = tcol * BN;

    // staging geometry: per K-tile 16KB A-tile + 16KB B-tile; wave w covers
    // rows w*32..w*32+31 via 2 gload_lds each for A and B.
    // dest byte d = j*1024 + lane*16 -> drow = j*16+(lane>>2), dcol=(lane&3)*16.
    // inverse-swizzled SOURCE col byte = dcol ^ ((drow>>1)&3)<<4.
    const int arow0 = w * 32 + (lane >> 2);
    const int arow1 = arow0 + 16;
    const int lcb0  = ((lane & 3) * 16) ^ (((arow0 >> 1) & 3) << 4);
    const int lcb1  = ((lane & 3) * 16) ^ (((arow1 >> 1) & 3) << 4);
    const ushort_t* srcA0 = Hb + (size_t)(r0 + arow0) * DIM + (lcb0 >> 1);
    const ushort_t* srcA1 = Hb + (size_t)(r0 + arow1) * DIM + (lcb1 >> 1);
    const ushort_t* srcB0 = Eb + (size_t)(n0 + arow0) * DIM + (lcb0 >> 1);
    const ushort_t* srcB1 = Eb + (size_t)(n0 + arow1) * DIM + (lcb1 >> 1);
    const int j0u = (w * 2) * 512;
    const int j1u = (w * 2 + 1) * 512;

    // swizzled ds_read bases (byte offsets within a slot)
    const int swz   = ((r_ >> 1) & 3) << 4;
    const int abase = (wr * 128 + r_) * 64 + ((g * 16) ^ swz);   // + m*1024
    const int bbase = (wc * 64  + r_) * 64 + ((g * 16) ^ swz);   // + n*1024

    f32x4 acc[8][4];
    #pragma unroll
    for (int m = 0; m < 8; ++m)
        #pragma unroll
        for (int n = 0; n < 4; ++n) acc[m][n] = (f32x4){0.f, 0.f, 0.f, 0.f};

#define STAGE_A(T) do {                                             \
        const int _ko = (T) * BK;                                   \
        gload_lds16(srcA0 + _ko, &As[(T) & 3][j0u]);                \
        gload_lds16(srcA1 + _ko, &As[(T) & 3][j1u]);                \
    } while (0)
#define STAGE_B(T) do {                                             \
        const int _ko = (T) * BK;                                   \
        gload_lds16(srcB0 + _ko, &Bs[(T) & 3][j0u]);                \
        gload_lds16(srcB1 + _ko, &Bs[(T) & 3][j1u]);                \
    } while (0)
#define MF(M, N, AV, BV) \
        acc[M][N] = __builtin_amdgcn_mfma_f32_16x16x32_bf16(AV, BV, acc[M][N], 0, 0, 0)

#define K_TILE(KT, VMSTR) do {                                      \
        if ((KT) + 2 < NT) STAGE_A((KT) + 2);                       \
        asm volatile("s_waitcnt vmcnt(" VMSTR ")" ::: "memory");    \
        __builtin_amdgcn_s_barrier();                               \
        const char* Ab = (const char*)&As[(KT) & 3][0];             \
        const char* Bb = (const char*)&Bs[(KT) & 3][0];             \
        bf16x8 a0 = *(const bf16x8*)(Ab + abase + 0 * 1024);        \
        bf16x8 a1 = *(const bf16x8*)(Ab + abase + 1 * 1024);        \
        bf16x8 a2 = *(const bf16x8*)(Ab + abase + 2 * 1024);        \
        bf16x8 a3 = *(const bf16x8*)(Ab + abase + 3 * 1024);        \
        bf16x8 a4 = *(const bf16x8*)(Ab + abase + 4 * 1024);        \
        bf16x8 a5 = *(const bf16x8*)(Ab + abase + 5 * 1024);        \
        bf16x8 a6 = *(const bf16x8*)(Ab + abase + 6 * 1024);        \
        bf16x8 a7 = *(const bf16x8*)(Ab + abase + 7 * 1024);        \
        bf16x8 b0 = *(const bf16x8*)(Bb + bbase + 0 * 1024);        \
        bf16x8 b1 = *(const bf16x8*)(Bb + bbase + 1 * 1024);        \
        bf16x8 b2 = *(const bf16x8*)(Bb + bbase + 2 * 1024);        \
        bf16x8 b3 = *(const bf16x8*)(Bb + bbase + 3 * 1024);        \
        __builtin_amdgcn_s_setprio(1);                              \
        MF(0, 0, a0, b0); MF(0, 1, a0, b1); MF(0, 2, a0, b2); MF(0, 3, a0, b3); \
        MF(1, 0, a1, b0); MF(1, 1, a1, b1); MF(1, 2, a1, b2); MF(1, 3, a1, b3); \
        MF(2, 0, a2, b0); MF(2, 1, a2, b1); MF(2, 2, a2, b2); MF(2, 3, a2, b3); \
        MF(3, 0, a3, b0); MF(3, 1, a3, b1); MF(3, 2, a3, b2); MF(3, 3, a3, b3); \
        __builtin_amdgcn_s_setprio(0);                              \
        if ((KT) + 2 < NT) STAGE_B((KT) + 2);                       \
        __builtin_amdgcn_s_setprio(1);                              \
        MF(4, 0, a4, b0); MF(4, 1, a4, b1); MF(4, 2, a4, b2); MF(4, 3, a4, b3); \
        MF(5, 0, a5, b0); MF(5, 1, a5, b1); MF(5, 2, a5, b2); MF(5, 3, a5, b3); \
        MF(6, 0, a6, b0); MF(6, 1, a6, b1); MF(6, 2, a6, b2); MF(6, 3, a6, b3); \
        MF(7, 0, a7, b0); MF(7, 1, a7, b1); MF(7, 2, a7, b2); MF(7, 3, a7, b3); \
        __builtin_amdgcn_s_setprio(0);                              \
    } while (0)

    // prologue: tiles 0 and 1 fully staged (8 loads in flight)
    STAGE_A(0); STAGE_B(0);
    STAGE_A(1); STAGE_B(1);

    K_TILE(0,  "6");
    K_TILE(1,  "6");
    K_TILE(2,  "6");
    K_TILE(3,  "6");
    K_TILE(4,  "6");
    K_TILE(5,  "6");
    K_TILE(6,  "6");
    K_TILE(7,  "6");
    K_TILE(8,  "6");
    K_TILE(9,  "6");
    K_TILE(10, "6");
    K_TILE(11, "6");
    K_TILE(12, "6");
    K_TILE(13, "6");
    K_TILE(14, "4");
    K_TILE(15, "0");

#undef K_TILE
#undef MF
#undef STAGE_B
#undef STAGE_A

    // ---- epilogue: per-row top-2 over this wave's 64-col chunk ----
    const int cb = n0 + wc * 64;
    #pragma unroll
    for (int m = 0; m < 8; ++m) {
        #pragma unroll
        for (int reg = 0; reg < 4; ++reg) {
            float v1 = acc[m][0][reg]; int i1 = cb + r_;
            float v2 = -3.4e38f;       int i2 = 0;
            #pragma unroll
            for (int n = 1; n < 4; ++n) {
                float vv = acc[m][n][reg];
                int   cc = cb + n * 16 + r_;
                if (vv > v1)      { v2 = v1; i2 = i1; v1 = vv; i1 = cc; }
                else if (vv > v2) { v2 = vv; i2 = cc; }
            }
            #pragma unroll
            for (int off = 1; off < 16; off <<= 1) {
                float u1 = __shfl_xor(v1, off);
                int   j1 = __shfl_xor(i1, off);
                float u2 = __shfl_xor(v2, off);
                int   j2 = __shfl_xor(i2, off);
                if (u1 > v1) {
                    if (v1 > u2) { v2 = v1; i2 = i1; }
                    else         { v2 = u2; i2 = j2; }
                    v1 = u1; i1 = j1;
                } else if (u1 > v2) { v2 = u1; i2 = j1; }
            }
            if (r_ == 0) {
                const int row  = r0 + wr * 128 + m * 16 + g * 4 + reg;
                const size_t base = (size_t)row * 256 + (n0 >> 5) + wc * 2;
                pval[base] = v1; pval[base + 1] = v2;
                pidx[base] = i1; pidx[base + 1] = i2;
            }
        }
    }
}

// ---------- Kernel 3: exact fp32 re-check of candidates + gather ----------
__global__ __launch_bounds__(256) void finalize_kernel(
    const float* __restrict__ x, const float* __restrict__ lw,
    const float* __restrict__ lb, const float* __restrict__ embd,
    const float2* __restrict__ stats,
    const float* __restrict__ pval, const int* __restrict__ pidx,
    float* __restrict__ outq, float* __restrict__ outi)
{
    const int w    = threadIdx.x >> 6;
    const int lane = threadIdx.x & 63;
    const int row  = blockIdx.x * 4 + w;

    const float4 cv = *(const float4*)&pval[(size_t)row * 256 + lane * 4];
    const int4   ci = *(const int4*)  &pidx[(size_t)row * 256 + lane * 4];
    float vv[4] = { cv.x, cv.y, cv.z, cv.w };
    int   ii[4] = { ci.x, ci.y, ci.z, ci.w };

    float M = fmaxf(fmaxf(vv[0], vv[1]), fmaxf(vv[2], vv[3]));
    #pragma unroll
    for (int off = 1; off < 64; off <<= 1) M = fmaxf(M, __shfl_xor(M, off));
    const float T = M - MARGIN;

    const float2 st = stats[row];
    const float mu = st.x, rstd = st.y;
    const float* xr = x + (size_t)row * DIM + lane * 8;
    float4 x0 = *(const float4*)(xr);
    float4 x1 = *(const float4*)(xr + 4);
    float4 w0 = *(const float4*)(lw + lane * 8);
    float4 w1 = *(const float4*)(lw + lane * 8 + 4);
    float4 b0 = *(const float4*)(lb + lane * 8);
    float4 b1 = *(const float4*)(lb + lane * 8 + 4);
    float h[8] = {
        (x0.x - mu) * rstd * w0.x + b0.x, (x0.y - mu) * rstd * w0.y + b0.y,
        (x0.z - mu) * rstd * w0.z + b0.z, (x0.w - mu) * rstd * w0.w + b0.w,
        (x1.x - mu) * rstd * w1.x + b1.x, (x1.y - mu) * rstd * w1.y + b1.y,
        (x1.z - mu) * rstd * w1.z + b1.z, (x1.w - mu) * rstd * w1.w + b1.w };

    float bestv = -3.4e38f; int besti = 0x7fffffff;
    #pragma unroll
    for (int s = 0; s < 4; ++s) {
        unsigned long long msk = __ballot(vv[s] >= T);
        while (msk) {
            const int L = __ffsll(msk) - 1;
            msk &= msk - 1;
            const int cand = __shfl(ii[s], L);
            const float* er = embd + (size_t)cand * DIM + lane * 8;
            float4 e0 = *(const float4*)er;
            float4 e1 = *(const float4*)(er + 4);
            float d = h[0]*e0.x + h[1]*e0.y + h[2]*e0.z + h[3]*e0.w
                    + h[4]*e1.x + h[5]*e1.y + h[6]*e1.z + h[7]*e1.w;
            #pragma unroll
            for (int off = 1; off < 64; off <<= 1) d += __shfl_xor(d, off);
            if (d > bestv || (d == bestv && cand < besti)) { bestv = d; besti = cand; }
        }
    }

    const float* er = embd + (size_t)besti * DIM + lane * 8;
    float4 q0 = *(const float4*)er;
    float4 q1 = *(const float4*)(er + 4);
    float* qr = outq + (size_t)row * DIM + lane * 8;
    *(float4*)(qr)     = q0;
    *(float4*)(qr + 4) = q1;
    if (lane == 0) outi[row] = (float)besti;
}

extern "C" void kernel_launch(void* const* d_in, const int* in_sizes, int n_in,
                              void* d_out, int out_size, void* d_ws, size_t ws_size,
                              hipStream_t stream) {
    const float* x    = (const float*)d_in[0];
    const float* lnw  = (const float*)d_in[1];
    const float* lnb  = (const float*)d_in[2];
    const float* embd = (const float*)d_in[3];

    float* outq = (float*)d_out;
    float* outi = outq + (size_t)ROWS * DIM;

    char* ws = (char*)d_ws;
    float2*   stats = (float2*)ws;                                   // 64 KiB
    ushort_t* Hb    = (ushort_t*)(ws + (1 << 16));                   // 8 MiB
    ushort_t* Eb    = (ushort_t*)(ws + (1 << 16) + (8 << 20));       // 8 MiB
    float*    pval  = (float*)(ws + (1 << 16) + (16 << 20));         // 8 MiB
    int*      pidx  = (int*)  (ws + (1 << 16) + (24 << 20));         // 8 MiB

    prep_kernel<<<4096, 256, 0, stream>>>(x, lnw, lnb, embd, stats, Hb, Eb);

    gemm_argmax_kernel<<<1024, 512, 0, stream>>>(Hb, Eb, pval, pidx);

    finalize_kernel<<<ROWS / 4, 256, 0, stream>>>(x, lnw, lnb, embd, stats,
                                                  pval, pidx, outq, outi);
}